// Round 5
// baseline (178.070 us; speedup 1.0000x reference)
//
#include <hip/hip_runtime.h>
#include <math.h>

#define HD 128
#define WD 128
#define LD 512
#define NHD 128
#define HW (HD*WD)

typedef _Float16 half8 __attribute__((ext_vector_type(8)));
typedef float floatx4 __attribute__((ext_vector_type(4)));
typedef float floatx16 __attribute__((ext_vector_type(16)));

// ---------------- workspace layout (float offsets) ----------------
#define OFF_MU      0                      // [B][F][L]                  10240
#define OFF_TG      10240                  // [B][6][9][64]              13824
#define OFF_TB      24064                  // [B][6][9][64]              13824
#define OFF_MEAN    37888                  // [256]
#define OFF_RSTD    38144                  // [256]
#define OFF_CT      38400                  // fp32 [2][9][512][64]       589824
#define OFF_W3      628224                 // f16 frag [2][9][2][8][64][8] = 73728 f
#define OFF_ACTVH   701952                 // f16 [B][H][W][NH] = 4194304 f
#define OFF_IDX_BYTES ((size_t)(701952 + 4194304) * 4)   // u8 [B][H][W]

// mask-patch LDS offset for conv-k (k = c*9 + ky*3 + kx), compile-time in unrolled loops
__device__ constexpr int mloff(int k) {
    return ((k / 9) * 3 + ((k % 9) / 3)) * 66 + ((k % 9) % 3);
}

// ================= k_pre1: all independent preprocessing =====================
// [0,256)    S1: CT build   [o][c][tap] -> [tbl][tap][c][o]  (LDS transpose)
// [256,288)  S2: W3 build   spade weights -> pre-scaled f16 wave fragments
// [288,448)  S3: style mu = relu(fc(codes))
// [448,704)  S4: idx map
// [704,960)  S5: instance-norm stats
// [960,1984) S6: shared conv -> actv NHWC f16   (MFMA implicit GEMM)
__global__ void __launch_bounds__(256) k_pre1(
    const float* __restrict__ x, const float* __restrict__ segmap,
    const float* __restrict__ codes, const float* __restrict__ mask,
    const float* __restrict__ fc_w, const float* __restrict__ fc_b,
    const float* __restrict__ cgw, const float* __restrict__ cbw,
    const float* __restrict__ sgw, const float* __restrict__ sbw,
    const float* __restrict__ ssw, const float* __restrict__ ssb,
    const float* __restrict__ bgam, const float* __restrict__ bbet,
    float* __restrict__ mu, float* __restrict__ CT, _Float16* __restrict__ W3,
    unsigned char* __restrict__ idxm, float* __restrict__ meanp,
    float* __restrict__ rstdp, _Float16* __restrict__ actvh) {
    int bid = blockIdx.x, t = threadIdx.x;

    if (bid < 256) {                      // ---- S1: CT transpose via LDS tile
        __shared__ float sl[64][37];
        int tbl = bid >> 7, cq4 = bid & 127;
        const float* src = tbl ? cbw : cgw;          // [64][512][9]
        int o = t >> 2, q = t & 3;
        const float* sp = src + (size_t)o * 4608 + cq4 * 36 + q * 9;
        #pragma unroll
        for (int j = 0; j < 9; ++j) sl[o][q * 9 + j] = sp[j];
        __syncthreads();
        int o_w = t & 63, s = t >> 6;                // s = c sub-index 0..3
        float* dst = CT + (size_t)tbl * 294912;
        #pragma unroll
        for (int tap = 0; tap < 9; ++tap)
            dst[((size_t)tap * 512 + cq4 * 4 + s) * 64 + o_w] = sl[o_w][s * 9 + tap];
        return;
    }
    if (bid < 288) {                      // ---- S2: W3 fragment build (pre-scaled)
        __shared__ _Float16 sl2[32][145];
        int e2 = bid - 256;               // tbl*16 + ocg*8 + chq
        int tbl = e2 >> 4, ocg = (e2 >> 3) & 1, chq = e2 & 7;   // chq = 16-ch group
        const float* src = tbl ? sbw : sgw;          // [64][128][9]
        float blg = 1.f / (1.f + __expf(-bgam[0]));
        float blb = 1.f / (1.f + __expf(-bbet[0]));
        float scale = tbl ? (1.f - blb) : (1.f - blg);
        int oc_r = t >> 3, i = t & 7;
        const float* sp = src + (size_t)(ocg * 32 + oc_r) * 1152 + chq * 144 + i * 18;
        #pragma unroll
        for (int j = 0; j < 18; ++j) sl2[oc_r][i * 18 + j] = (_Float16)(sp[j] * scale);
        __syncthreads();
        for (int s = 0; s < 3; ++s) {
            int task = s * 256 + t;                   // tap*64 + ln, 576 tasks
            if (task < 576) {
                int tap = task >> 6, ln = task & 63;
                int lo = ln & 31, hb = ln >> 5;
                half8 hv;
                #pragma unroll
                for (int j = 0; j < 8; ++j)
                    hv[j] = sl2[lo][(hb * 8 + j) * 9 + tap];
                *(half8*)(W3 + ((((size_t)tbl * 9 + tap) * 2 + ocg) * 8 + chq) * 512
                          + ln * 8) = hv;
            }
        }
        return;
    }
    if (bid < 448) {                      // ---- S3: style
        __shared__ float cs[LD];
        int sid = bid - 288;              // bf*8 + chunk
        int bf = sid >> 3, chunk = sid & 7, f = bf % 5;
        cs[t] = codes[(size_t)bf * LD + t];
        cs[t + 256] = codes[(size_t)bf * LD + t + 256];
        __syncthreads();
        int row = t >> 2, lane4 = t & 3;
        int k = chunk * 64 + row;
        const float* wrow = fc_w + ((size_t)f * LD + k) * LD;
        float acc = 0.f;
        for (int j = 0; j < 32; ++j) {
            int l = lane4 * 4 + j * 16;
            float4 wv = *(const float4*)(wrow + l);
            float4 cv = *(const float4*)(cs + l);
            acc += wv.x * cv.x + wv.y * cv.y + wv.z * cv.z + wv.w * cv.w;
        }
        acc += __shfl_xor(acc, 1);
        acc += __shfl_xor(acc, 2);
        if (lane4 == 0)
            mu[(size_t)bf * LD + k] = fmaxf(acc + fc_b[f * LD + k], 0.f);
        return;
    }
    if (bid < 704) {                      // ---- S4: idx
        int pid = (bid - 448) * 256 + t;
        int b = pid >> 14, p = pid & 16383;
        unsigned char v = 5;
        for (int f = 0; f < 5; ++f)
            if (segmap[((size_t)b * 5 + f) * HW + p] > 0.f) v = (unsigned char)f;
        idxm[pid] = v;
        return;
    }
    if (bid < 960) {                      // ---- S5: stats
        __shared__ float as[4], as2[4];
        int plane = bid - 704;
        const float* xp = x + (size_t)plane * HW;
        float s = 0.f, s2 = 0.f;
        for (int j = 0; j < 16; ++j) {
            float4 v = *(const float4*)(xp + ((size_t)t + j * 256) * 4);
            s += v.x + v.y + v.z + v.w;
            s2 += v.x * v.x + v.y * v.y + v.z * v.z + v.w * v.w;
        }
        for (int off = 32; off; off >>= 1) { s += __shfl_xor(s, off); s2 += __shfl_xor(s2, off); }
        int wid = t >> 6;
        if ((t & 63) == 0) { as[wid] = s; as2[wid] = s2; }
        __syncthreads();
        if (t == 0) {
            s = as[0] + as[1] + as[2] + as[3];
            s2 = as2[0] + as2[1] + as2[2] + as2[3];
            float m = s * (1.f / HW);
            float var = s2 * (1.f / HW) - m * m;
            meanp[plane] = m;
            rstdp[plane] = rsqrtf(var + 1e-5f);
        }
        return;
    }
    {                                     // ---- S6: shared conv via MFMA
        __shared__ float ml[3][3][66];    // mask patch [c][ky][col]
        __shared__ _Float16 Bs2[4096];    // B frags [kgrp(4)][oc(128)][8]
        __shared__ _Float16 Cbuf[8192];   // [px(64)][oc(128)]
        int sid = bid - 960;
        int xh = sid & 1, h = (sid >> 1) & 127, b = sid >> 8;
        int w0 = xh * 64;
        for (int e = t; e < 594; e += 256) {
            int col = e % 66; int rc = e / 66; int ky = rc % 3; int c = rc / 3;
            int y = h - 1 + ky; int xx = w0 - 1 + col;
            float v = 0.f;
            if ((unsigned)y < 128u && (unsigned)xx < 128u)
                v = mask[(((size_t)b * 3 + c) * HD + y) * WD + xx];
            ml[c][ky][col] = v;
        }
        for (int e = t; e < 512; e += 256) {          // Bs2 from ssw [oc][27]
            int ks = e >> 8, hb = (e >> 7) & 1, oc = e & 127;
            int kb = ks * 16 + hb * 8;
            half8 hv;
            #pragma unroll
            for (int j = 0; j < 8; ++j)
                hv[j] = (kb + j < 27) ? (_Float16)ssw[oc * 27 + kb + j] : (_Float16)0.f;
            *(half8*)(&Bs2[(size_t)e * 8]) = hv;
        }
        __syncthreads();
        int lane = t & 63, wv = t >> 6;
        int l31 = lane & 31, hb = lane >> 5;
        int oc = wv * 32 + l31;
        const float* mlf = &ml[0][0][0];
        floatx16 acc[2];
        #pragma unroll
        for (int i = 0; i < 16; ++i) { acc[0][i] = 0.f; acc[1][i] = 0.f; }
        #pragma unroll
        for (int ks = 0; ks < 2; ++ks) {
            half8 bfrag = *(const half8*)(&Bs2[((ks * 2 + hb) * 128 + oc) * 8]);
            #pragma unroll
            for (int mf = 0; mf < 2; ++mf) {
                int px = mf * 32 + l31;
                half8 a;
                #pragma unroll
                for (int j = 0; j < 8; ++j) {
                    int k_lo = ks * 16 + j;           // lane hb=0
                    int k_hi = k_lo + 8;              // lane hb=1
                    float v;
                    if (k_hi < 27)
                        v = mlf[(hb ? mloff(18 + (k_lo - (k_lo / 9) * 9) + ((k_lo / 9) == 0 ? -9 : -9)) : 0) + 0]; // placeholder (never taken path rewritten below)
                    // rewritten cleanly below
                    if (k_hi < 27)
                        v = hb ? mlf[mloff(k_hi) + px] : mlf[mloff(k_lo) + px];
                    else
                        v = hb ? 0.f : mlf[mloff(k_lo) + px];
                    a[j] = (_Float16)v;
                }
                acc[mf] = __builtin_amdgcn_mfma_f32_32x32x16_f16(a, bfrag, acc[mf], 0, 0, 0);
            }
        }
        float bv = ssb[oc];
        #pragma unroll
        for (int mf = 0; mf < 2; ++mf)
            #pragma unroll
            for (int q = 0; q < 4; ++q)
                #pragma unroll
                for (int r = 0; r < 4; ++r) {
                    int px = mf * 32 + 8 * q + 4 * hb + r;
                    Cbuf[px * 128 + oc] = (_Float16)fmaxf(acc[mf][q * 4 + r] + bv, 0.f);
                }
        __syncthreads();
        for (int e = t; e < 1024; e += 256) {
            int px = e >> 4, ch8 = e & 15;
            *(half8*)(actvh + (((size_t)b * HD + h) * WD + w0 + px) * NHD + ch8 * 8) =
                *(const half8*)(&Cbuf[px * 128 + ch8 * 8]);
        }
    }
}

// ================= k_pre2: T tables (1024 thr for latency hiding) ============
__global__ void __launch_bounds__(1024) k_pre2(
    const float* __restrict__ mu, const float* __restrict__ CT,
    float* __restrict__ Tg, float* __restrict__ Tb) {
    int bid = blockIdx.x;                 // ((b*6+f)*9+tap), 216 blocks
    int tap = bid % 9; int bf6 = bid / 9;
    int f = bf6 % 6, b = bf6 / 6;
    int t = threadIdx.x;
    size_t base = (size_t)bid * 64;
    if (f == 5) {
        if (t < 64) { Tg[base + t] = 0.f; Tb[base + t] = 0.f; }
        return;
    }
    __shared__ float ms[LD];
    __shared__ float red[2][16][64];
    if (t < 512) ms[t] = mu[(((size_t)b * 5 + f) << 9) + t];
    __syncthreads();
    int o = t & 63, cq = t >> 6;          // cq 0..15
    const float* cg = CT + ((size_t)tap * 512 + cq * 32) * 64 + o;
    const float* cb = cg + 294912;
    float ag = 0.f, ab = 0.f;
    #pragma unroll 8
    for (int i = 0; i < 32; ++i) {
        float m = ms[cq * 32 + i];
        ag = fmaf(m, cg[(size_t)i * 64], ag);
        ab = fmaf(m, cb[(size_t)i * 64], ab);
    }
    red[0][cq][o] = ag; red[1][cq][o] = ab;
    __syncthreads();
    if (t < 128) {
        int tb2 = t >> 6, oo = t & 63;
        float s = 0.f;
        #pragma unroll
        for (int i = 0; i < 16; ++i) s += red[tb2][i][oo];
        (tb2 ? Tb : Tg)[base + oo] = s;
    }
}

// ================= k_main: 32x32x16 MFMA, fused spade+table GEMM =============
// 512 blocks (XCD swizzle), 256 thr = 4 waves. Tile: 2 rows x 64 cols = 128 px.
// Wave w: one 32-px m-frag (row_l=w>>1, c32=(w&1)*32), ALL 4 n-frags {2ocg x 2tbl}
// -> each A ds_read feeds 4 MFMAs (LDS-pipe balance).
__global__ void __launch_bounds__(256, 3)
k_main(const float* __restrict__ x, const _Float16* __restrict__ actvh,
       const unsigned char* __restrict__ idxm,
       const float* __restrict__ Tg, const float* __restrict__ Tb,
       const _Float16* __restrict__ W3,
       const float* __restrict__ meanp, const float* __restrict__ rstdp,
       const float* __restrict__ cgb, const float* __restrict__ cbb,
       const float* __restrict__ sgb, const float* __restrict__ sbb,
       const float* __restrict__ bgam, const float* __restrict__ bbet,
       float* __restrict__ out) {
    __shared__ _Float16 As[4 * 66 * 64];      // 33792 B, one 64-ch half
    __shared__ _Float16 T2f[8192];            // 16384 B table fragments
    __shared__ unsigned char ir[4][68];
    int t = threadIdx.x;

    int gid = blockIdx.x;                     // 512 = 8 XCD x 64
    int logical = (gid & 7) * 64 + (gid >> 3);
    int c64 = logical & 1, rp = (logical >> 1) & 63, b = logical >> 7;
    int w0 = c64 * 64, y0 = rp * 2;

    int lane = t & 63, w = t >> 6;            // 4 waves
    int row_l = w >> 1, c32 = (w & 1) * 32;
    int l31 = lane & 31, hi = lane >> 5;

    float ga = 1.f / (1.f + __expf(-bgam[0]));
    float ba = 1.f / (1.f + __expf(-bbet[0]));

    // ---- stage ir (region indices incl. halo)
    for (int e = t; e < 264; e += 256) {
        int r = e / 66, j = e % 66;
        int y = y0 - 1 + r, xx = w0 + j - 1;
        ir[r][j] = ((unsigned)y < 128u && (unsigned)xx < 128u)
                       ? idxm[((size_t)b << 14) + (y << 7) + xx] : (unsigned char)5;
    }
    // ---- stage T2f: table-B fragments [tbl][ocg][ks][lane][8], scaled ga/ba
    for (int task = t; task < 1024; task += 256) {
        int tbl = task >> 9, rem = task & 511;
        int ocs = rem >> 8, ks = (rem >> 6) & 3, ln = rem & 63;
        int oc = ocs * 32 + (ln & 31);
        int kb = ks * 16 + (ln >> 5) * 8;
        const float* Tsrc = tbl ? Tb : Tg;
        float sc = tbl ? ba : ga;
        half8 hv;
        #pragma unroll
        for (int j = 0; j < 8; ++j) {
            int k = kb + j;
            int f = (k * 57) >> 9;            // floor(k/9), exact for k<64
            int tp = k - f * 9;
            float v = (f < 6) ? Tsrc[(((size_t)b * 6 + f) * 9 + tp) * 64 + oc] * sc : 0.f;
            hv[j] = (_Float16)v;
        }
        *(half8*)(&T2f[task * 8]) = hv;
    }

    floatx16 accg[2], accb[2];                // [ocg]
    #pragma unroll
    for (int i = 0; i < 16; ++i) {
        accg[0][i] = 0.f; accg[1][i] = 0.f;
        accb[0][i] = 0.f; accb[1][i] = 0.f;
    }

    // ---- main spade GEMM: 2 ch-halves x 9 taps x 4 ksteps x {2ocg x 2tbl}
    for (int half = 0; half < 2; ++half) {
        int ch0 = half * 64;
        for (int e = t; e < 2112; e += 256) {          // stage As (4x66x64 f16)
            int ch8 = e & 7, col = (e >> 3) % 66, row = e / 528;
            int y = y0 - 1 + row, xx = w0 - 1 + col;
            uint4 v = make_uint4(0u, 0u, 0u, 0u);
            if ((unsigned)y < 128u && (unsigned)xx < 128u)
                v = *(const uint4*)(actvh + ((((size_t)b * HD + y) * WD + xx) << 7)
                                    + ch0 + ch8 * 8);
            *(uint4*)(&As[((row * 66 + col) << 6) + ((ch8 ^ (col & 7)) << 3)]) = v;
        }
        __syncthreads();
        #pragma unroll
        for (int tap = 0; tap < 9; ++tap) {
            int ky = tap / 3, kx = tap - ky * 3;
            int colA = c32 + l31 + kx;
            int rowA = row_l + ky;
            int abase = (rowA * 66 + colA) << 6;
            int sw = colA & 7;
            const _Float16* wg0 = W3 + (((size_t)tap * 2 + 0) * 8 + half * 4) * 512
                                  + lane * 8;
            const _Float16* wg1 = W3 + (((size_t)tap * 2 + 1) * 8 + half * 4) * 512
                                  + lane * 8;
            #pragma unroll
            for (int ks = 0; ks < 4; ++ks) {
                half8 a = *(const half8*)(&As[abase + (((ks * 2 + hi) ^ sw) << 3)]);
                half8 bg0 = *(const half8*)(wg0 + ks * 512);
                half8 bg1 = *(const half8*)(wg1 + ks * 512);
                half8 bb0 = *(const half8*)(wg0 + 73728 + ks * 512);
                half8 bb1 = *(const half8*)(wg1 + 73728 + ks * 512);
                accg[0] = __builtin_amdgcn_mfma_f32_32x32x16_f16(a, bg0, accg[0], 0, 0, 0);
                accg[1] = __builtin_amdgcn_mfma_f32_32x32x16_f16(a, bg1, accg[1], 0, 0, 0);
                accb[0] = __builtin_amdgcn_mfma_f32_32x32x16_f16(a, bb0, accb[0], 0, 0, 0);
                accb[1] = __builtin_amdgcn_mfma_f32_32x32x16_f16(a, bb1, accb[1], 0, 0, 0);
            }
        }
        __syncthreads();
    }

    // ---- table GEMM: one-hot A (from ir) x T2f fragments, K=64
    unsigned long long fpack = 0ull;
    #pragma unroll
    for (int ky = 0; ky < 3; ++ky)
        #pragma unroll
        for (int kx = 0; kx < 3; ++kx) {
            unsigned long long f = ir[row_l + ky][c32 + l31 + kx];
            fpack |= f << ((ky * 3 + kx) * 6);
        }
    #pragma unroll
    for (int ks = 0; ks < 4; ++ks) {
        int kb = ks * 16 + hi * 8;
        half8 a1;
        #pragma unroll
        for (int j = 0; j < 8; ++j) {
            int k = kb + j;
            int f = (k * 57) >> 9;
            int tp6 = (k - f * 9) * 6;
            int fp = (int)((fpack >> tp6) & 63ull);
            a1[j] = (fp == f) ? (_Float16)1.0f : (_Float16)0.0f;
        }
        #pragma unroll
        for (int ocg = 0; ocg < 2; ++ocg) {
            half8 bg = *(const half8*)(&T2f[((ocg * 4 + ks) * 64 + lane) * 8]);
            half8 bb = *(const half8*)(&T2f[(((2 + ocg) * 4 + ks) * 64 + lane) * 8]);
            accg[ocg] = __builtin_amdgcn_mfma_f32_32x32x16_f16(a1, bg, accg[ocg], 0, 0, 0);
            accb[ocg] = __builtin_amdgcn_mfma_f32_32x32x16_f16(a1, bb, accb[ocg], 0, 0, 0);
        }
    }

    // ---- final: instance-norm + folded-blend biases + store
    #pragma unroll
    for (int ocg = 0; ocg < 2; ++ocg) {
        int oc = ocg * 32 + l31;
        int plane = b * 64 + oc;
        float mean = meanp[plane], rstd = rstdp[plane];
        float gbias = ga * cgb[oc] + (1.f - ga) * sgb[oc];
        float bbias = ba * cbb[oc] + (1.f - ba) * sbb[oc];
        size_t rowoff = (size_t)plane * HW + (y0 + row_l) * WD + w0 + c32;
        const float* xrow = x + rowoff;
        float* orow = out + rowoff;
        #pragma unroll
        for (int q = 0; q < 4; ++q) {
            int p0 = 8 * q + 4 * hi;              // C/D row = (reg&3)+8*(reg>>2)+4*hi
            float4 xv = *(const float4*)(xrow + p0);
            float xa[4] = {xv.x, xv.y, xv.z, xv.w};
            float res[4];
            #pragma unroll
            for (int r2 = 0; r2 < 4; ++r2) {
                float gf = accg[ocg][q * 4 + r2] + gbias;
                float bf = accb[ocg][q * 4 + r2] + bbias;
                res[r2] = (xa[r2] - mean) * rstd * (1.f + gf) + bf;
            }
            *(float4*)(orow + p0) = make_float4(res[0], res[1], res[2], res[3]);
        }
    }
}

extern "C" void kernel_launch(void* const* d_in, const int* in_sizes, int n_in,
                              void* d_out, int out_size, void* d_ws, size_t ws_size,
                              hipStream_t stream) {
    const float* x      = (const float*)d_in[0];
    const float* segmap = (const float*)d_in[1];
    const float* codes  = (const float*)d_in[2];
    const float* mask   = (const float*)d_in[3];
    const float* fc_w   = (const float*)d_in[4];
    const float* fc_b   = (const float*)d_in[5];
    const float* cgw    = (const float*)d_in[6];
    const float* cgb    = (const float*)d_in[7];
    const float* cbw    = (const float*)d_in[8];
    const float* cbb    = (const float*)d_in[9];
    const float* ssw    = (const float*)d_in[10];
    const float* ssb    = (const float*)d_in[11];
    const float* sgw    = (const float*)d_in[12];
    const float* sgb    = (const float*)d_in[13];
    const float* sbw    = (const float*)d_in[14];
    const float* sbb    = (const float*)d_in[15];
    const float* bgam   = (const float*)d_in[16];
    const float* bbet   = (const float*)d_in[17];
    float* out = (float*)d_out;

    float* wsf = (float*)d_ws;
    float* mu    = wsf + OFF_MU;
    float* Tg    = wsf + OFF_TG;
    float* Tb    = wsf + OFF_TB;
    float* meanp = wsf + OFF_MEAN;
    float* rstdp = wsf + OFF_RSTD;
    float* CT    = wsf + OFF_CT;
    _Float16* W3    = (_Float16*)(wsf + OFF_W3);
    _Float16* actvh = (_Float16*)(wsf + OFF_ACTVH);
    unsigned char* idxm = (unsigned char*)d_ws + OFF_IDX_BYTES;

    k_pre1<<<1984, 256, 0, stream>>>(x, segmap, codes, mask, fc_w, fc_b,
                                     cgw, cbw, sgw, sbw, ssw, ssb, bgam, bbet,
                                     mu, CT, W3, idxm, meanp, rstdp, actvh);
    k_pre2<<<216, 1024, 0, stream>>>(mu, CT, Tg, Tb);
    k_main<<<512, 256, 0, stream>>>(x, actvh, idxm, Tg, Tb, W3,
                                    meanp, rstdp, cgb, cbb, sgb, sbb,
                                    bgam, bbet, out);
}

// Round 6
// 154.074 us; speedup vs baseline: 1.1557x; 1.1557x over previous
//
#include <hip/hip_runtime.h>
#include <math.h>

#define HD 128
#define WD 128
#define LD 512
#define NHD 128
#define HW (HD*WD)

typedef _Float16 half8 __attribute__((ext_vector_type(8)));
typedef float floatx16 __attribute__((ext_vector_type(16)));

// ---------------- workspace layout (float offsets) ----------------
#define OFF_MU      0                      // [B][F][L]                  10240
#define OFF_TG      10240                  // [B][6][9][64]              13824
#define OFF_TB      24064                  // [B][6][9][64]              13824
#define OFF_MEAN    37888                  // [256]
#define OFF_RSTD    38144                  // [256]
#define OFF_CT      38400                  // fp32 [2][9][512][64]       589824
#define OFF_W3      628224                 // f16 frag [2][9][2][8][64][8] = 73728 f
#define OFF_ACTVH   701952                 // f16 [B][H][W][NH] = 4194304 f
#define OFF_IDX_BYTES ((size_t)(701952 + 4194304) * 4)   // u8 [B][H][W]

// mask-patch LDS offset for conv-k (k = c*9 + ky*3 + kx), compile-time in unrolled loops
__device__ constexpr int mloff(int k) {
    return ((k / 9) * 3 + ((k % 9) / 3)) * 66 + ((k % 9) % 3);
}

// ================= k_pre1: all independent preprocessing =====================
// [0,256)    S1: CT build   [o][c][tap] -> [tbl][tap][c][o]  (LDS transpose)
// [256,288)  S2: W3 build   spade weights -> pre-scaled f16 wave fragments
// [288,448)  S3: style mu = relu(fc(codes))
// [448,704)  S4: idx map
// [704,960)  S5: instance-norm stats
// [960,1984) S6: shared conv -> actv NHWC f16   (MFMA implicit GEMM)
__global__ void __launch_bounds__(256) k_pre1(
    const float* __restrict__ x, const float* __restrict__ segmap,
    const float* __restrict__ codes, const float* __restrict__ mask,
    const float* __restrict__ fc_w, const float* __restrict__ fc_b,
    const float* __restrict__ cgw, const float* __restrict__ cbw,
    const float* __restrict__ sgw, const float* __restrict__ sbw,
    const float* __restrict__ ssw, const float* __restrict__ ssb,
    const float* __restrict__ bgam, const float* __restrict__ bbet,
    float* __restrict__ mu, float* __restrict__ CT, _Float16* __restrict__ W3,
    unsigned char* __restrict__ idxm, float* __restrict__ meanp,
    float* __restrict__ rstdp, _Float16* __restrict__ actvh) {
    int bid = blockIdx.x, t = threadIdx.x;

    if (bid < 256) {                      // ---- S1: CT transpose via LDS tile
        __shared__ float sl[64][37];
        int tbl = bid >> 7, cq4 = bid & 127;
        const float* src = tbl ? cbw : cgw;          // [64][512][9]
        int o = t >> 2, q = t & 3;
        const float* sp = src + (size_t)o * 4608 + cq4 * 36 + q * 9;
        #pragma unroll
        for (int j = 0; j < 9; ++j) sl[o][q * 9 + j] = sp[j];
        __syncthreads();
        int o_w = t & 63, s = t >> 6;                // s = c sub-index 0..3
        float* dst = CT + (size_t)tbl * 294912;
        #pragma unroll
        for (int tap = 0; tap < 9; ++tap)
            dst[((size_t)tap * 512 + cq4 * 4 + s) * 64 + o_w] = sl[o_w][s * 9 + tap];
        return;
    }
    if (bid < 288) {                      // ---- S2: W3 fragment build (pre-scaled)
        __shared__ _Float16 sl2[32][145];
        int e2 = bid - 256;               // tbl*16 + ocg*8 + chq
        int tbl = e2 >> 4, ocg = (e2 >> 3) & 1, chq = e2 & 7;   // chq = 16-ch group
        const float* src = tbl ? sbw : sgw;          // [64][128][9]
        float blg = 1.f / (1.f + __expf(-bgam[0]));
        float blb = 1.f / (1.f + __expf(-bbet[0]));
        float scale = tbl ? (1.f - blb) : (1.f - blg);
        int oc_r = t >> 3, i = t & 7;
        const float* sp = src + (size_t)(ocg * 32 + oc_r) * 1152 + chq * 144 + i * 18;
        #pragma unroll
        for (int j = 0; j < 18; ++j) sl2[oc_r][i * 18 + j] = (_Float16)(sp[j] * scale);
        __syncthreads();
        for (int s = 0; s < 3; ++s) {
            int task = s * 256 + t;                   // tap*64 + ln, 576 tasks
            if (task < 576) {
                int tap = task >> 6, ln = task & 63;
                int lo = ln & 31, hb = ln >> 5;
                half8 hv;
                #pragma unroll
                for (int j = 0; j < 8; ++j)
                    hv[j] = sl2[lo][(hb * 8 + j) * 9 + tap];
                *(half8*)(W3 + ((((size_t)tbl * 9 + tap) * 2 + ocg) * 8 + chq) * 512
                          + ln * 8) = hv;
            }
        }
        return;
    }
    if (bid < 448) {                      // ---- S3: style
        __shared__ float cs[LD];
        int sid = bid - 288;              // bf*8 + chunk
        int bf = sid >> 3, chunk = sid & 7, f = bf % 5;
        cs[t] = codes[(size_t)bf * LD + t];
        cs[t + 256] = codes[(size_t)bf * LD + t + 256];
        __syncthreads();
        int row = t >> 2, lane4 = t & 3;
        int k = chunk * 64 + row;
        const float* wrow = fc_w + ((size_t)f * LD + k) * LD;
        float acc = 0.f;
        for (int j = 0; j < 32; ++j) {
            int l = lane4 * 4 + j * 16;
            float4 wv = *(const float4*)(wrow + l);
            float4 cv = *(const float4*)(cs + l);
            acc += wv.x * cv.x + wv.y * cv.y + wv.z * cv.z + wv.w * cv.w;
        }
        acc += __shfl_xor(acc, 1);
        acc += __shfl_xor(acc, 2);
        if (lane4 == 0)
            mu[(size_t)bf * LD + k] = fmaxf(acc + fc_b[f * LD + k], 0.f);
        return;
    }
    if (bid < 704) {                      // ---- S4: idx
        int pid = (bid - 448) * 256 + t;
        int b = pid >> 14, p = pid & 16383;
        unsigned char v = 5;
        for (int f = 0; f < 5; ++f)
            if (segmap[((size_t)b * 5 + f) * HW + p] > 0.f) v = (unsigned char)f;
        idxm[pid] = v;
        return;
    }
    if (bid < 960) {                      // ---- S5: stats
        __shared__ float as[4], as2[4];
        int plane = bid - 704;
        const float* xp = x + (size_t)plane * HW;
        float s = 0.f, s2 = 0.f;
        for (int j = 0; j < 16; ++j) {
            float4 v = *(const float4*)(xp + ((size_t)t + j * 256) * 4);
            s += v.x + v.y + v.z + v.w;
            s2 += v.x * v.x + v.y * v.y + v.z * v.z + v.w * v.w;
        }
        for (int off = 32; off; off >>= 1) { s += __shfl_xor(s, off); s2 += __shfl_xor(s2, off); }
        int wid = t >> 6;
        if ((t & 63) == 0) { as[wid] = s; as2[wid] = s2; }
        __syncthreads();
        if (t == 0) {
            s = as[0] + as[1] + as[2] + as[3];
            s2 = as2[0] + as2[1] + as2[2] + as2[3];
            float m = s * (1.f / HW);
            float var = s2 * (1.f / HW) - m * m;
            meanp[plane] = m;
            rstdp[plane] = rsqrtf(var + 1e-5f);
        }
        return;
    }
    {                                     // ---- S6: shared conv via MFMA
        __shared__ float ml[3][3][66];    // mask patch [c][ky][col]
        __shared__ _Float16 Bs2[4096];    // B frags [kgrp(4)][oc(128)][8]
        __shared__ _Float16 Cbuf[8192];   // [px(64)][oc(128)]
        int sid = bid - 960;
        int xh = sid & 1, h = (sid >> 1) & 127, b = sid >> 8;
        int w0 = xh * 64;
        for (int e = t; e < 594; e += 256) {
            int col = e % 66; int rc = e / 66; int ky = rc % 3; int c = rc / 3;
            int y = h - 1 + ky; int xx = w0 - 1 + col;
            float v = 0.f;
            if ((unsigned)y < 128u && (unsigned)xx < 128u)
                v = mask[(((size_t)b * 3 + c) * HD + y) * WD + xx];
            ml[c][ky][col] = v;
        }
        for (int e = t; e < 512; e += 256) {          // Bs2 from ssw [oc][27]
            int ks = e >> 8, hb = (e >> 7) & 1, oc = e & 127;
            int kb = ks * 16 + hb * 8;
            half8 hv;
            #pragma unroll
            for (int j = 0; j < 8; ++j)
                hv[j] = (kb + j < 27) ? (_Float16)ssw[oc * 27 + kb + j] : (_Float16)0.f;
            *(half8*)(&Bs2[(size_t)e * 8]) = hv;
        }
        __syncthreads();
        int lane = t & 63, wv = t >> 6;
        int l31 = lane & 31, hb = lane >> 5;
        int oc = wv * 32 + l31;
        const float* mlf = &ml[0][0][0];
        floatx16 acc[2];
        #pragma unroll
        for (int i = 0; i < 16; ++i) { acc[0][i] = 0.f; acc[1][i] = 0.f; }
        #pragma unroll
        for (int ks = 0; ks < 2; ++ks) {
            half8 bfrag = *(const half8*)(&Bs2[((ks * 2 + hb) * 128 + oc) * 8]);
            #pragma unroll
            for (int mf = 0; mf < 2; ++mf) {
                int px = mf * 32 + l31;
                half8 a;
                #pragma unroll
                for (int j = 0; j < 8; ++j) {
                    int k_lo = ks * 16 + j;           // lane hb=0 reads k_lo
                    int k_hi = k_lo + 8;              // lane hb=1 reads k_hi
                    float v;
                    if (k_hi < 27)
                        v = hb ? mlf[mloff(k_hi) + px] : mlf[mloff(k_lo) + px];
                    else
                        v = hb ? 0.f : mlf[mloff(k_lo) + px];
                    a[j] = (_Float16)v;
                }
                acc[mf] = __builtin_amdgcn_mfma_f32_32x32x16_f16(a, bfrag, acc[mf], 0, 0, 0);
            }
        }
        float bv = ssb[oc];
        #pragma unroll
        for (int mf = 0; mf < 2; ++mf)
            #pragma unroll
            for (int q = 0; q < 4; ++q)
                #pragma unroll
                for (int r = 0; r < 4; ++r) {
                    int px = mf * 32 + 8 * q + 4 * hb + r;
                    Cbuf[px * 128 + oc] = (_Float16)fmaxf(acc[mf][q * 4 + r] + bv, 0.f);
                }
        __syncthreads();
        for (int e = t; e < 1024; e += 256) {
            int px = e >> 4, ch8 = e & 15;
            *(half8*)(actvh + (((size_t)b * HD + h) * WD + w0 + px) * NHD + ch8 * 8) =
                *(const half8*)(&Cbuf[px * 128 + ch8 * 8]);
        }
    }
}

// ================= k_pre2: T tables (1024 thr for latency hiding) ============
__global__ void __launch_bounds__(1024) k_pre2(
    const float* __restrict__ mu, const float* __restrict__ CT,
    float* __restrict__ Tg, float* __restrict__ Tb) {
    int bid = blockIdx.x;                 // ((b*6+f)*9+tap), 216 blocks
    int tap = bid % 9; int bf6 = bid / 9;
    int f = bf6 % 6, b = bf6 / 6;
    int t = threadIdx.x;
    size_t base = (size_t)bid * 64;
    if (f == 5) {
        if (t < 64) { Tg[base + t] = 0.f; Tb[base + t] = 0.f; }
        return;
    }
    __shared__ float ms[LD];
    __shared__ float red[2][16][64];
    if (t < 512) ms[t] = mu[(((size_t)b * 5 + f) << 9) + t];
    __syncthreads();
    int o = t & 63, cq = t >> 6;          // cq 0..15
    const float* cg = CT + ((size_t)tap * 512 + cq * 32) * 64 + o;
    const float* cb = cg + 294912;
    float ag = 0.f, ab = 0.f;
    #pragma unroll 8
    for (int i = 0; i < 32; ++i) {
        float m = ms[cq * 32 + i];
        ag = fmaf(m, cg[(size_t)i * 64], ag);
        ab = fmaf(m, cb[(size_t)i * 64], ab);
    }
    red[0][cq][o] = ag; red[1][cq][o] = ab;
    __syncthreads();
    if (t < 128) {
        int tb2 = t >> 6, oo = t & 63;
        float s = 0.f;
        #pragma unroll
        for (int i = 0; i < 16; ++i) s += red[tb2][i][oo];
        (tb2 ? Tb : Tg)[base + oo] = s;
    }
}

// ================= k_main v3: LDS-resident operands, pipelined B =============
// 256 blocks (XCD swizzle) x 512 thr = 8 waves. Tile: 4 rows x 64 cols = 256 px,
// all 64 oc, both tbl. Wave w: mh=w>>1 (row mh, 2 m-frags), nh=w&1 (oc half).
// As = full-K [6 row][66 col][128 ch] staged ONCE (101 KB, XOR-swizzled).
// Bs = 2 x 16 KB double buffer, register-prefetched 2 iters ahead (18 iters).
// Per kstep: 4 ds_read_b128 + 4 MFMA (1.0 KB LDS / MFMA).
__global__ void __launch_bounds__(512, 2)
k_main(const float* __restrict__ x, const _Float16* __restrict__ actvh,
       const unsigned char* __restrict__ idxm,
       const float* __restrict__ Tg, const float* __restrict__ Tb,
       const _Float16* __restrict__ W3,
       const float* __restrict__ meanp, const float* __restrict__ rstdp,
       const float* __restrict__ cgb, const float* __restrict__ cbb,
       const float* __restrict__ sgb, const float* __restrict__ sbb,
       const float* __restrict__ bgam, const float* __restrict__ bbet,
       float* __restrict__ out) {
    __shared__ _Float16 As[50688];        // 101376 B: [6][66][128] swizzled
    __shared__ _Float16 Bs[16384];        // 32768 B: 2 bufs x [16 seg][512]
    __shared__ _Float16 T2f[8192];        // 16384 B table fragments
    __shared__ unsigned char ir[6][66];
    int t = threadIdx.x;

    int gid = blockIdx.x;                 // 256 = 8 XCD x 32, bijective
    int logical = (gid & 7) * 32 + (gid >> 3);
    int c64 = logical & 1, rp = (logical >> 1) & 31, b = logical >> 6;
    int w0 = c64 * 64, y0 = rp * 4;

    int lane = t & 63, w = t >> 6;
    int mh = w >> 1, nh = w & 1;
    int l31 = lane & 31, hi = lane >> 5;

    // B staging role: thread t owns 32 B of segment seg = t>>5
    int seg = t >> 5, lo32 = t & 31;
    int tbl_s = seg >> 3, ocg_s = (seg >> 2) & 1, kq_s = seg & 3;

    float ga = 1.f / (1.f + __expf(-bgam[0]));
    float ba = 1.f / (1.f + __expf(-bbet[0]));

    // ---- issue B(0) loads (half 0, tap 0)
    uint4 bpA0, bpA1, bpB0, bpB1;
    {
        const _Float16* gp = W3 + ((((size_t)tbl_s * 9 + 0) * 2 + ocg_s) * 8
                                   + 0 * 4 + kq_s) * 512 + lo32 * 16;
        bpA0 = *(const uint4*)gp; bpA1 = *(const uint4*)(gp + 8);
    }

    // ---- stage ir (region indices incl. halo)
    if (t < 396) {
        int r = t / 66, j = t - r * 66;
        int y = y0 - 1 + r, xx = w0 + j - 1;
        ir[r][j] = ((unsigned)y < 128u && (unsigned)xx < 128u)
                       ? idxm[((size_t)b << 14) + (y << 7) + xx] : (unsigned char)5;
    }

    // ---- stage As: full 128-ch, zero-padded borders, XOR ch8-group swizzle
    for (int e = t; e < 6336; e += 512) {
        int ch8 = e & 15, col = (e >> 4) % 66, row = e / 1056;
        int y = y0 - 1 + row, xx = w0 - 1 + col;
        uint4 v = make_uint4(0u, 0u, 0u, 0u);
        if ((unsigned)y < 128u && (unsigned)xx < 128u)
            v = *(const uint4*)(actvh + ((((size_t)b * HD + y) * WD + xx) << 7) + ch8 * 8);
        *(uint4*)(&As[((row * 66 + col) << 7) + ((ch8 ^ (col & 7)) << 3)]) = v;
    }

    // ---- stage T2f: table-B fragments [tbl*2+ocg][ks][lane][8], scaled ga/ba
    for (int task = t; task < 1024; task += 512) {
        int tbl = task >> 9, rem = task & 511;
        int ocs = rem >> 8, ks = (rem >> 6) & 3, ln = rem & 63;
        int oc = ocs * 32 + (ln & 31);
        int kb = ks * 16 + (ln >> 5) * 8;
        const float* Tsrc = tbl ? Tb : Tg;
        float sc = tbl ? ba : ga;
        half8 hv;
        #pragma unroll
        for (int j = 0; j < 8; ++j) {
            int k = kb + j;
            int f = (k * 57) >> 9;            // floor(k/9), exact for k<64
            int tp = k - f * 9;
            float v = (f < 6) ? Tsrc[(((size_t)b * 6 + f) * 9 + tp) * 64 + oc] * sc : 0.f;
            hv[j] = (_Float16)v;
        }
        *(half8*)(&T2f[task * 8]) = hv;
    }

    // ---- issue B(1) loads (half 0, tap 1)
    {
        const _Float16* gp = W3 + ((((size_t)tbl_s * 9 + 1) * 2 + ocg_s) * 8
                                   + 0 * 4 + kq_s) * 512 + lo32 * 16;
        bpB0 = *(const uint4*)gp; bpB1 = *(const uint4*)(gp + 8);
    }
    // ---- write B(0) -> buf0 (waits its loads via vmcnt dep)
    {
        _Float16* lp = Bs + seg * 512 + lo32 * 16;
        *(uint4*)lp = bpA0; *(uint4*)(lp + 8) = bpA1;
    }
    __syncthreads();

    floatx16 accg[2], accb[2];            // [mi]
    #pragma unroll
    for (int i = 0; i < 16; ++i) {
        accg[0][i] = 0.f; accg[1][i] = 0.f;
        accb[0][i] = 0.f; accb[1][i] = 0.f;
    }

    int cur = 0;
    for (int i = 0; i < 18; ++i) {
        // write B(i+1) (prefetched last iter) into buf cur^1
        if (i + 1 < 18) {
            _Float16* lp = Bs + (cur ^ 1) * 8192 + seg * 512 + lo32 * 16;
            if ((i + 1) & 1) { *(uint4*)lp = bpB0; *(uint4*)(lp + 8) = bpB1; }
            else             { *(uint4*)lp = bpA0; *(uint4*)(lp + 8) = bpA1; }
        }
        // issue B(i+2) loads into the just-freed register set ((i+2)&1 == i&1)
        if (i + 2 < 18) {
            int i2 = i + 2, hf2 = i2 / 9, tap2 = i2 - hf2 * 9;
            const _Float16* gp = W3 + ((((size_t)tbl_s * 9 + tap2) * 2 + ocg_s) * 8
                                       + hf2 * 4 + kq_s) * 512 + lo32 * 16;
            if (i & 1) { bpB0 = *(const uint4*)gp; bpB1 = *(const uint4*)(gp + 8); }
            else       { bpA0 = *(const uint4*)gp; bpA1 = *(const uint4*)(gp + 8); }
        }
        // compute from buf cur
        int hf = i / 9, tap = i - hf * 9;
        int ky = tap / 3, kx = tap - ky * 3;
        int colA = l31 + kx;
        int ra = ((mh + ky) * 66 + colA) << 7;
        int sw = colA & 7;
        const _Float16* Bcur = Bs + cur * 8192 + (nh << 11) + (lane << 3);
        #pragma unroll
        for (int ks = 0; ks < 4; ++ks) {
            int gsel = (((hf * 8 + ks * 2) + hi) ^ sw) << 3;
            half8 a0 = *(const half8*)(&As[ra + gsel]);
            half8 a1 = *(const half8*)(&As[ra + (32 << 7) + gsel]);
            half8 bgv = *(const half8*)(Bcur + (ks << 9));
            half8 bbv = *(const half8*)(Bcur + 4096 + (ks << 9));
            accg[0] = __builtin_amdgcn_mfma_f32_32x32x16_f16(a0, bgv, accg[0], 0, 0, 0);
            accg[1] = __builtin_amdgcn_mfma_f32_32x32x16_f16(a1, bgv, accg[1], 0, 0, 0);
            accb[0] = __builtin_amdgcn_mfma_f32_32x32x16_f16(a0, bbv, accb[0], 0, 0, 0);
            accb[1] = __builtin_amdgcn_mfma_f32_32x32x16_f16(a1, bbv, accb[1], 0, 0, 0);
        }
        __syncthreads();
        cur ^= 1;
    }

    // ---- table GEMM: one-hot A (from ir) x T2f fragments, K=64
    unsigned long long fp0 = 0ull, fp1 = 0ull;
    #pragma unroll
    for (int ky = 0; ky < 3; ++ky)
        #pragma unroll
        for (int kx = 0; kx < 3; ++kx) {
            int sh = (ky * 3 + kx) * 6;
            fp0 |= (unsigned long long)ir[mh + ky][l31 + kx] << sh;
            fp1 |= (unsigned long long)ir[mh + ky][32 + l31 + kx] << sh;
        }
    #pragma unroll
    for (int ks = 0; ks < 4; ++ks) {
        int kb = ks * 16 + hi * 8;
        half8 bg = *(const half8*)(&T2f[((nh * 4 + ks) * 64 + lane) * 8]);
        half8 bb = *(const half8*)(&T2f[(((2 + nh) * 4 + ks) * 64 + lane) * 8]);
        half8 a0, a1;
        #pragma unroll
        for (int j = 0; j < 8; ++j) {
            int k = kb + j;
            int f = (k * 57) >> 9;
            int tp6 = (k - f * 9) * 6;
            a0[j] = ((int)((fp0 >> tp6) & 63ull) == f) ? (_Float16)1.0f : (_Float16)0.0f;
            a1[j] = ((int)((fp1 >> tp6) & 63ull) == f) ? (_Float16)1.0f : (_Float16)0.0f;
        }
        accg[0] = __builtin_amdgcn_mfma_f32_32x32x16_f16(a0, bg, accg[0], 0, 0, 0);
        accg[1] = __builtin_amdgcn_mfma_f32_32x32x16_f16(a1, bg, accg[1], 0, 0, 0);
        accb[0] = __builtin_amdgcn_mfma_f32_32x32x16_f16(a0, bb, accb[0], 0, 0, 0);
        accb[1] = __builtin_amdgcn_mfma_f32_32x32x16_f16(a1, bb, accb[1], 0, 0, 0);
    }

    // ---- final: instance-norm + folded-blend biases + store
    int oc = nh * 32 + l31;
    int plane = b * 64 + oc;
    float mean = meanp[plane], rstd = rstdp[plane];
    float gbias = ga * cgb[oc] + (1.f - ga) * sgb[oc];
    float bbias = ba * cbb[oc] + (1.f - ba) * sbb[oc];
    int row = y0 + mh;
    #pragma unroll
    for (int mi = 0; mi < 2; ++mi) {
        size_t rowoff = (size_t)plane * HW + (size_t)row * WD + w0 + mi * 32;
        #pragma unroll
        for (int q = 0; q < 4; ++q) {
            int p0 = 8 * q + 4 * hi;          // C/D row = (reg&3)+8*(reg>>2)+4*hi
            float4 xv = *(const float4*)(x + rowoff + p0);
            float xa[4] = {xv.x, xv.y, xv.z, xv.w};
            float res[4];
            #pragma unroll
            for (int r2 = 0; r2 < 4; ++r2) {
                float gf = (mi ? accg[1][q * 4 + r2] : accg[0][q * 4 + r2]) + gbias;
                float bf = (mi ? accb[1][q * 4 + r2] : accb[0][q * 4 + r2]) + bbias;
                res[r2] = (xa[r2] - mean) * rstd * (1.f + gf) + bf;
            }
            *(float4*)(out + rowoff + p0) = make_float4(res[0], res[1], res[2], res[3]);
        }
    }
}

extern "C" void kernel_launch(void* const* d_in, const int* in_sizes, int n_in,
                              void* d_out, int out_size, void* d_ws, size_t ws_size,
                              hipStream_t stream) {
    const float* x      = (const float*)d_in[0];
    const float* segmap = (const float*)d_in[1];
    const float* codes  = (const float*)d_in[2];
    const float* mask   = (const float*)d_in[3];
    const float* fc_w   = (const float*)d_in[4];
    const float* fc_b   = (const float*)d_in[5];
    const float* cgw    = (const float*)d_in[6];
    const float* cgb    = (const float*)d_in[7];
    const float* cbw    = (const float*)d_in[8];
    const float* cbb    = (const float*)d_in[9];
    const float* ssw    = (const float*)d_in[10];
    const float* ssb    = (const float*)d_in[11];
    const float* sgw    = (const float*)d_in[12];
    const float* sgb    = (const float*)d_in[13];
    const float* sbw    = (const float*)d_in[14];
    const float* sbb    = (const float*)d_in[15];
    const float* bgam   = (const float*)d_in[16];
    const float* bbet   = (const float*)d_in[17];
    float* out = (float*)d_out;

    float* wsf = (float*)d_ws;
    float* mu    = wsf + OFF_MU;
    float* Tg    = wsf + OFF_TG;
    float* Tb    = wsf + OFF_TB;
    float* meanp = wsf + OFF_MEAN;
    float* rstdp = wsf + OFF_RSTD;
    float* CT    = wsf + OFF_CT;
    _Float16* W3    = (_Float16*)(wsf + OFF_W3);
    _Float16* actvh = (_Float16*)(wsf + OFF_ACTVH);
    unsigned char* idxm = (unsigned char*)d_ws + OFF_IDX_BYTES;

    k_pre1<<<1984, 256, 0, stream>>>(x, segmap, codes, mask, fc_w, fc_b,
                                     cgw, cbw, sgw, sbw, ssw, ssb, bgam, bbet,
                                     mu, CT, W3, idxm, meanp, rstdp, actvh);
    k_pre2<<<216, 1024, 0, stream>>>(mu, CT, Tg, Tb);
    k_main<<<256, 512, 0, stream>>>(x, actvh, idxm, Tg, Tb, W3,
                                    meanp, rstdp, cgb, cbb, sgb, sbb,
                                    bgam, bbet, out);
}